// Round 1
// 58.987 us; speedup vs baseline: 1.0246x; 1.0246x over previous
//
#include <hip/hip_runtime.h>

// Persistence image: out[b,d,i,j] = sum_p w_p * exp(-50*((x_i-birth_p)^2 + (y_j-pers_p)^2))
// with w_p = max(pers_p, 0), pers_p = death_p - birth_p, x_i = i/19, y_j = j/19.
//
// v2: transposed LDS tables (point-minor) so phase 2 reads 4 points per ds_read_b128,
// 2x2 cell tile per thread (rows ig/ig+10 x jg/jg+10 -> distinct bank groups at
// stride 260), and slot-range split across wave pairs with an LDS reduction.
// Phase-2 LDS issue: 8 -> 2 wave-instr per point per block.

#define RX 20
#define RY 20
#define SPLIT 8        // blocks per (b,d); 96*8 = 768 = 3 blocks/CU exactly
#define CHUNK 256      // points per block (one per thread in phase 1)
#define PST 260        // transposed row stride in floats: 16B-aligned, 260%32=4

__global__ __launch_bounds__(256) void pimg_kernel(const float2* __restrict__ pd,
                                                   float* __restrict__ out,
                                                   int n_bd) {
    __shared__ __attribute__((aligned(16))) float s_gxT[RX * PST]; // [i][slot]
    __shared__ __attribute__((aligned(16))) float s_gyT[RY * PST]; // [j][slot]
    __shared__ int s_wave_cnt[4];
    __shared__ float s_red[100 * 5];   // stride 5: conflict-free scalar exchange

    const int tid   = threadIdx.x;
    const int bd    = blockIdx.x / SPLIT;
    const int chunk = blockIdx.x % SPLIT;
    const int pbase = bd * 2048 + chunk * CHUNK;

    // ---- Phase 1: load one point per thread, compact active (pers>0) into LDS tables
    float2 p2  = pd[pbase + tid];        // (birth, death), coalesced 8B/lane
    float birth = p2.x;
    float pers  = p2.y - p2.x;
    bool active = pers > 0.0f;

    unsigned long long mask = __ballot(active);
    int lane = tid & 63;
    int wid  = tid >> 6;
    int rank = __popcll(mask & ((1ull << lane) - 1ull));
    if (lane == 0) s_wave_cnt[wid] = __popcll(mask);
    __syncthreads();

    int offset = 0;
    #pragma unroll
    for (int w = 0; w < 4; ++w)
        if (w < wid) offset += s_wave_cnt[w];
    int total = s_wave_cnt[0] + s_wave_cnt[1] + s_wave_cnt[2] + s_wave_cnt[3];
    int tp = (total + 3) & ~3;           // pad to multiple of 4 for float4 phase 2

    if (active) {
        int slot = offset + rank;        // lanes write consecutive slots: conflict-free
        #pragma unroll
        for (int i = 0; i < RX; ++i) {
            float xi = i * (1.0f / 19.0f);
            float dx = xi - birth;
            float dy = xi - pers;
            s_gxT[i * PST + slot] = pers * __expf(-50.0f * dx * dx);
            s_gyT[i * PST + slot] =        __expf(-50.0f * dy * dy);
        }
    }
    // zero the pad slots [total, tp) so the float4 tail contributes exactly 0
    if (tid >= total && tid < tp) {
        #pragma unroll
        for (int i = 0; i < RX; ++i) {
            s_gxT[i * PST + tid] = 0.0f;
            s_gyT[i * PST + tid] = 0.0f;
        }
    }
    __syncthreads();

    // ---- Phase 2: 2x2 cell tile per thread; slot range split across wave pairs.
    // threads 0..99   (waves 0-1): slots [0, s_mid)
    // threads 128..227 (waves 2-3): slots [s_mid, tp)
    const int half = tid >> 7;
    const int t100 = tid & 127;
    float a00 = 0.0f, a01 = 0.0f, a10 = 0.0f, a11 = 0.0f;
    int ig = 0, jg = 0;
    if (t100 < 100) {
        ig = t100 / 10;                  // gx rows ig, ig+10: bank groups 4ig, 4ig+8 (distinct)
        jg = t100 % 10;                  // gy rows jg, jg+10: worst 2-way (free)
        int s_mid = (tp >> 1) & ~3;
        int s0 = half ? s_mid : 0;
        int s1 = half ? tp    : s_mid;
        const float* gxa = &s_gxT[ ig       * PST];
        const float* gxb = &s_gxT[(ig + 10) * PST];
        const float* gya = &s_gyT[ jg       * PST];
        const float* gyb = &s_gyT[(jg + 10) * PST];
        for (int s = s0; s < s1; s += 4) {
            float4 xa = *(const float4*)(gxa + s);
            float4 xb = *(const float4*)(gxb + s);
            float4 ya = *(const float4*)(gya + s);
            float4 yb = *(const float4*)(gyb + s);
            a00 = fmaf(xa.x, ya.x, a00); a00 = fmaf(xa.y, ya.y, a00);
            a00 = fmaf(xa.z, ya.z, a00); a00 = fmaf(xa.w, ya.w, a00);
            a01 = fmaf(xa.x, yb.x, a01); a01 = fmaf(xa.y, yb.y, a01);
            a01 = fmaf(xa.z, yb.z, a01); a01 = fmaf(xa.w, yb.w, a01);
            a10 = fmaf(xb.x, ya.x, a10); a10 = fmaf(xb.y, ya.y, a10);
            a10 = fmaf(xb.z, ya.z, a10); a10 = fmaf(xb.w, ya.w, a10);
            a11 = fmaf(xb.x, yb.x, a11); a11 = fmaf(xb.y, yb.y, a11);
            a11 = fmaf(xb.z, yb.z, a11); a11 = fmaf(xb.w, yb.w, a11);
        }
    }
    // upper wave-pair hands its partials to the lower one
    if (half == 1 && t100 < 100) {
        s_red[t100 * 5 + 0] = a00;
        s_red[t100 * 5 + 1] = a01;
        s_red[t100 * 5 + 2] = a10;
        s_red[t100 * 5 + 3] = a11;
    }
    __syncthreads();
    if (half == 0 && t100 < 100) {
        a00 += s_red[t100 * 5 + 0];
        a01 += s_red[t100 * 5 + 1];
        a10 += s_red[t100 * 5 + 2];
        a11 += s_red[t100 * 5 + 3];
        float* o = out + bd * (RX * RY);
        atomicAdd(o +  ig       * RY + jg,      a00);
        atomicAdd(o +  ig       * RY + jg + 10, a01);
        atomicAdd(o + (ig + 10) * RY + jg,      a10);
        atomicAdd(o + (ig + 10) * RY + jg + 10, a11);
    }
}

extern "C" void kernel_launch(void* const* d_in, const int* in_sizes, int n_in,
                              void* d_out, int out_size, void* d_ws, size_t ws_size,
                              hipStream_t stream) {
    const float2* pd = (const float2*)d_in[0];
    float* out = (float*)d_out;
    int n_bd = in_sizes[0] / (2048 * 2);   // 32*3 = 96
    hipMemsetAsync(d_out, 0, (size_t)out_size * sizeof(float), stream);
    pimg_kernel<<<dim3(n_bd * SPLIT), dim3(256), 0, stream>>>(pd, out, n_bd);
}